// Round 8
// baseline (255.194 us; speedup 1.0000x reference)
//
#include <hip/hip_runtime.h>
#include <hip/hip_cooperative_groups.h>
#include <math.h>

namespace cg = cooperative_groups;

// B=8, C=64, H=W=64, O=64, K=3, KK=9, HW=4096
// Single cooperative kernel:
//   Phase A: NCHW fp32 -> catT[b][hw][128] bf16 transpose + MFMA A-frag
//            weight packing (math identical to round 7).
//   grid.sync()
//   Phase B: per-wave fused om conv (K=1152) -> wave-private transpose ->
//            deformable conv (K=576). Orientation HW-validated rounds 4-7:
//     A = weights: lane(l16,lq) holds W[m=tile*16+l16][k=step*32+lq*8+j]
//     B = samples: lane(l16,lq) holds S[k=step*32+lq*8+j][n=px(l16)]
//     C/D: col(=px)=lane&15, row(=m)=(lane>>4)*4+reg
//
// ws layout (shorts):
//   [0,     36864)  wd_pk : idx=((s*4+lq)*64+o)*8+j, s=t*2+qh (18)
//   [36864, 73728)  wo_pk : idx=((s*4+lq)*32+oc)*8+j, s=quarter*9+t (36)
//   [73728, +4194304B) catT bf16[b][hw][128] (feat c0..63, deg c64..127)
#define WO_PK_OFF 36864
#define CATT_OFF  73728

typedef short  short8  __attribute__((ext_vector_type(8)));
typedef float  float4v __attribute__((ext_vector_type(4)));

static __device__ __forceinline__ short f2bf(float f) {
    unsigned int u = __builtin_bit_cast(unsigned int, f);
    u += 0x7FFFu + ((u >> 16) & 1u);   // round-to-nearest-even
    return (short)(u >> 16);
}
static __device__ __forceinline__ float bf2f(unsigned short u) {
    return __builtin_bit_cast(float, (unsigned int)u << 16);
}

__global__ __launch_bounds__(256, 2) void mono_kernel(
    const float* __restrict__ feat, const float* __restrict__ deg,
    const float* __restrict__ weight, const float* __restrict__ om_weight,
    const float* __restrict__ om_bias,
    unsigned short* __restrict__ catT,
    short* __restrict__ wd_pk, short* __restrict__ wo_pk,
    float* __restrict__ out)
{
    __shared__ unsigned short T[64 * 136];     // 17,408 B (reused in phase B)
    const int tid = threadIdx.x;
    const int lane = tid & 63, wv = tid >> 6;

    // ================= Phase A: transpose + weight pack =================
    {
        const int b = blockIdx.x >> 6, h = blockIdx.x & 63;
#pragma unroll
        for (int cc = 0; cc < 32; cc++) {
            int c = wv * 32 + cc;              // wave-uniform
            const float* src = (c < 64)
                ? (feat + (size_t)(b * 64 + c) * 4096)
                : (deg  + (size_t)(b * 64 + (c - 64)) * 4096);
            T[lane * 136 + c] = (unsigned short)f2bf(src[h * 64 + lane]);
        }
        if (blockIdx.x < 288) {                // weight packing chunk
            int idx = blockIdx.x * 256 + tid;  // covers exactly 73728
            if (idx < 36864) {
                int j = idx & 7, o = (idx >> 3) & 63;
                int lq2 = (idx >> 9) & 3, ks = idx >> 11;
                int t = ks >> 1, c = (ks & 1) * 32 + lq2 * 8 + j;
                wd_pk[idx] = f2bf(weight[(o * 64 + c) * 9 + t]);
            } else {
                int e = idx - 36864;
                int j = e & 7, oc = (e >> 3) & 31;
                int lq2 = (e >> 8) & 3, ks2 = e >> 10;
                int quarter = ks2 / 9, t = ks2 - quarter * 9;
                int cg2 = quarter * 32 + lq2 * 8 + j;
                wo_pk[e] = (oc < 27) ? f2bf(om_weight[(oc * 128 + cg2) * 9 + t])
                                     : (short)0;
            }
        }
        __syncthreads();
        const int px = tid >> 2, seg = tid & 3;
        unsigned short* dst =
            catT + (size_t)(b * 4096 + h * 64 + px) * 128 + seg * 32;
#pragma unroll
        for (int j = 0; j < 4; j++)
            *(uint4*)(dst + j * 8) = *(const uint4*)&T[px * 136 + seg * 32 + j * 8];
    }
    __threadfence();
    cg::this_grid().sync();

    // ========================= Phase B: fused =========================
    const int l16 = lane & 15, lq = lane >> 4;
    const int gw = blockIdx.x * 4 + wv;
    const int b = gw >> 8, tile = gw & 255;
    const int h = tile >> 2, w0 = (tile & 3) << 4;
    const int pxx = w0 + l16;
    const unsigned short* cb = catT + (size_t)b * 4096 * 128;
    const short8 zf = {0, 0, 0, 0, 0, 0, 0, 0};

    // ---- phase 1: om conv, 3-deep prefetch ----
    auto loadB1 = [&](int s) -> short8 {
        int quarter = s / 9, t = s - quarter * 9;
        int ky = t / 3, kx = t - ky * 3;
        int yy = h - 1 + ky, xx = pxx - 1 + kx;
        bool ok = (yy >= 0) & (yy <= 63) & (xx >= 0) & (xx <= 63);
        int yc = min(max(yy, 0), 63), xc = min(max(xx, 0), 63);
        short8 v = *(const short8*)(cb + (yc * 64 + xc) * 128
                                       + quarter * 32 + lq * 8);
        return ok ? v : zf;
    };
    float4v oacc0 = {0.f, 0.f, 0.f, 0.f};
    float4v oacc1 = {0.f, 0.f, 0.f, 0.f};
    short8 pb[3];
    pb[0] = loadB1(0); pb[1] = loadB1(1); pb[2] = loadB1(2);
#pragma unroll
    for (int s = 0; s < 36; s++) {
        short8 bcur = pb[s % 3];
        if (s + 3 < 36) pb[s % 3] = loadB1(s + 3);
        const short8* Ap = (const short8*)(wo_pk + (size_t)(s * 4 + lq) * 256);
        oacc0 = __builtin_amdgcn_mfma_f32_16x16x32_bf16(Ap[l16],      bcur, oacc0, 0, 0, 0);
        oacc1 = __builtin_amdgcn_mfma_f32_16x16x32_bf16(Ap[16 + l16], bcur, oacc1, 0, 0, 0);
    }

    // ---- phase 2: wave-private transpose -> omv[27] ----
    float* Tw = (float*)T + wv * 576;          // 9,216 B of the 17,408 B
    __syncthreads();                           // phase A LDS fully consumed
#pragma unroll
    for (int r = 0; r < 4; r++) {
        Tw[l16 * 36 + lq * 4 + r]      = oacc0[r];   // oc = lq*4+r
        Tw[l16 * 36 + 16 + lq * 4 + r] = oacc1[r];   // oc = 16+lq*4+r
    }
    __syncthreads();
    float omv[28];
#pragma unroll
    for (int jj = 0; jj < 7; jj++)
        *(float4v*)&omv[jj * 4] = *(const float4v*)&Tw[l16 * 36 + jj * 4];
#pragma unroll
    for (int j = 0; j < 27; j++) omv[j] += om_bias[j];

    // ---- phase 3: deformable conv, coeff precompute + 2-deep pipeline ----
    float Wb[9][4];
    int   Ob[9][4];
#pragma unroll
    for (int t = 0; t < 9; t++) {
        const int ky = t / 3, kx = t - ky * 3;
        float dy = omv[2 * t], dx = omv[2 * t + 1];
        float mm = 1.f / (1.f + __expf(-omv[18 + t]));   // sigmoid(mask)
        float yf = (float)(h - 1 + ky) + dy;
        float xf = (float)(pxx - 1 + kx) + dx;
        float fy = floorf(yf), fx = floorf(xf);
        int y0 = (int)fy, x0 = (int)fx;
        float wy = yf - fy, wx = xf - fx;
        bool vy0 = (y0 >= 0) & (y0 < 64);
        bool vy1 = (y0 >= -1) & (y0 < 63);
        bool vx0 = (x0 >= 0) & (x0 < 64);
        bool vx1 = (x0 >= -1) & (x0 < 63);
        float a0 = (1.f - wy) * mm, a1 = wy * mm;
        Wb[t][0] = a0 * (1.f - wx) * (float)(vy0 & vx0);
        Wb[t][1] = a0 * wx         * (float)(vy0 & vx1);
        Wb[t][2] = a1 * (1.f - wx) * (float)(vy1 & vx0);
        Wb[t][3] = a1 * wx         * (float)(vy1 & vx1);
        // taps clamped INDEPENDENTLY: clamp(y0+1), not clamp(y0)+1
        int iy0 = min(max(y0, 0), 63),     ix0 = min(max(x0, 0), 63);
        int iy1 = min(max(y0 + 1, 0), 63), ix1 = min(max(x0 + 1, 0), 63);
        Ob[t][0] = (iy0 * 64 + ix0) * 128;  Ob[t][1] = (iy0 * 64 + ix1) * 128;
        Ob[t][2] = (iy1 * 64 + ix0) * 128;  Ob[t][3] = (iy1 * 64 + ix1) * 128;
    }

    float4v acc[4];
#pragma unroll
    for (int mt = 0; mt < 4; mt++) acc[mt] = (float4v){0.f, 0.f, 0.f, 0.f};

    auto loadC = [&](int s, short8* c) {
        int t = s >> 1, qh = s & 1;
        int cho = qh * 32 + lq * 8;            // feat channels only (<64)
#pragma unroll
        for (int r = 0; r < 4; r++)
            c[r] = *(const short8*)(cb + Ob[t][r] + cho);
    };
    short8 cb0[4], cb1[4];
    loadC(0, cb0);
    loadC(1, cb1);
#pragma unroll
    for (int s = 0; s < 18; s++) {
        short8* cur = (s & 1) ? cb1 : cb0;
        const int t = s >> 1;
        short8 bfr;
#pragma unroll
        for (int j = 0; j < 8; j++) {
            float v = Wb[t][0] * bf2f((unsigned short)cur[0][j])
                    + Wb[t][1] * bf2f((unsigned short)cur[1][j])
                    + Wb[t][2] * bf2f((unsigned short)cur[2][j])
                    + Wb[t][3] * bf2f((unsigned short)cur[3][j]);
            bfr[j] = f2bf(v);
        }
        if (s + 2 < 18) loadC(s + 2, cur);     // refill consumed buffer
        const short8* Dp = (const short8*)(wd_pk + (size_t)(s * 4 + lq) * 512);
        acc[0] = __builtin_amdgcn_mfma_f32_16x16x32_bf16(Dp[l16],      bfr, acc[0], 0, 0, 0);
        acc[1] = __builtin_amdgcn_mfma_f32_16x16x32_bf16(Dp[16 + l16], bfr, acc[1], 0, 0, 0);
        acc[2] = __builtin_amdgcn_mfma_f32_16x16x32_bf16(Dp[32 + l16], bfr, acc[2], 0, 0, 0);
        acc[3] = __builtin_amdgcn_mfma_f32_16x16x32_bf16(Dp[48 + l16], bfr, acc[3], 0, 0, 0);
    }

    // store: o = mt*16 + lq*4 + r, px = w0 + l16
    float* ob = out + (size_t)(b * 64) * 4096 + h * 64 + w0 + l16;
#pragma unroll
    for (int mt = 0; mt < 4; mt++)
#pragma unroll
        for (int r = 0; r < 4; r++)
            ob[(mt * 16 + lq * 4 + r) * 4096] = acc[mt][r];
}

extern "C" void kernel_launch(void* const* d_in, const int* in_sizes, int n_in,
                              void* d_out, int out_size, void* d_ws, size_t ws_size,
                              hipStream_t stream)
{
    const float* feat      = (const float*)d_in[0];
    const float* deg       = (const float*)d_in[1];
    const float* weight    = (const float*)d_in[2];
    const float* om_weight = (const float*)d_in[3];
    const float* om_bias   = (const float*)d_in[4];
    float* out = (float*)d_out;
    short* wss = (short*)d_ws;
    short* wd_pk = wss;
    short* wo_pk = wss + WO_PK_OFF;
    unsigned short* catT = (unsigned short*)(wss + CATT_OFF);

    void* args[] = {
        (void*)&feat, (void*)&deg, (void*)&weight, (void*)&om_weight,
        (void*)&om_bias, (void*)&catT, (void*)&wd_pk, (void*)&wo_pk,
        (void*)&out
    };
    hipLaunchCooperativeKernel((const void*)mono_kernel,
                               dim3(512), dim3(256), args, 0, stream);
}

// Round 9
// 119.337 us; speedup vs baseline: 2.1384x; 2.1384x over previous
//
#include <hip/hip_runtime.h>
#include <math.h>

// B=8, C=64, H=W=64, O=64, K=3, KK=9, HW=4096
// Two kernels:
//   prep_transpose: NCHW fp32 -> catT[b][hw][128] bf16 + MFMA A-frag weight
//                   packing (identical math to rounds 6-8, all verified).
//   fused_kernel:   per-wave (16 px): om conv (K=1152) -> wave-private
//                   transpose -> deformable conv (K=576).
// Orientation (HW-validated rounds 4-8):
//   A = weights: lane(l16,lq) holds W[m=tile*16+l16][k=step*32+lq*8+j]
//   B = samples: lane(l16,lq) holds S[k=step*32+lq*8+j][n=px(l16)]
//   C/D: col(=px)=lane&15, row(=m)=(lane>>4)*4+reg
//
// ROUND-9 RULE (learned from r8 counters: VGPR=64 + 14MB scratch writes):
// no local arrays, no lambdas writing through pointers — named regs only,
// so SROA keeps every prefetch buffer in VGPRs.
//
// ws layout (shorts):
//   [0,     36864)  wd_pk : idx=((s*4+lq)*64+o)*8+j, s=t*2+qh (18)
//   [36864, 73728)  wo_pk : idx=((s*4+lq)*32+oc)*8+j, s=quarter*9+t (36)
//   [73728, +4194304B) catT bf16[b][hw][128] (feat c0..63, deg c64..127)
#define WO_PK_OFF 36864
#define CATT_OFF  73728

typedef short  short8  __attribute__((ext_vector_type(8)));
typedef float  float4v __attribute__((ext_vector_type(4)));

static __device__ __forceinline__ short f2bf(float f) {
    unsigned int u = __builtin_bit_cast(unsigned int, f);
    u += 0x7FFFu + ((u >> 16) & 1u);   // round-to-nearest-even
    return (short)(u >> 16);
}
static __device__ __forceinline__ float bf2f(unsigned short u) {
    return __builtin_bit_cast(float, (unsigned int)u << 16);
}

// blocks [0,512): transpose; blocks [512,800): weight packing.
__global__ __launch_bounds__(256) void prep_transpose(
    const float* __restrict__ feat, const float* __restrict__ deg,
    const float* __restrict__ weight, const float* __restrict__ om_weight,
    unsigned short* __restrict__ catT,
    short* __restrict__ wd_pk, short* __restrict__ wo_pk)
{
    __shared__ unsigned short T[64 * 136];
    const int tid = threadIdx.x;
    if (blockIdx.x < 512) {
        const int b = blockIdx.x >> 6, h = blockIdx.x & 63;
        const int lane = tid & 63, wv = tid >> 6;
#pragma unroll
        for (int cc = 0; cc < 32; cc++) {
            int c = wv * 32 + cc;              // wave-uniform
            const float* src = (c < 64)
                ? (feat + (size_t)(b * 64 + c) * 4096)
                : (deg  + (size_t)(b * 64 + (c - 64)) * 4096);
            T[lane * 136 + c] = (unsigned short)f2bf(src[h * 64 + lane]);
        }
        __syncthreads();
        const int px = tid >> 2, seg = tid & 3;
        unsigned short* dst =
            catT + (size_t)(b * 4096 + h * 64 + px) * 128 + seg * 32;
#pragma unroll
        for (int j = 0; j < 4; j++)
            *(uint4*)(dst + j * 8) = *(const uint4*)&T[px * 136 + seg * 32 + j * 8];
    } else {
        int idx = (blockIdx.x - 512) * 256 + tid;   // covers exactly 73728
        if (idx < 36864) {
            int j = idx & 7, o = (idx >> 3) & 63;
            int lq = (idx >> 9) & 3, ks = idx >> 11;
            int t = ks >> 1, c = (ks & 1) * 32 + lq * 8 + j;
            wd_pk[idx] = f2bf(weight[(o * 64 + c) * 9 + t]);
        } else {
            int e = idx - 36864;
            int j = e & 7, oc = (e >> 3) & 31;
            int lq = (e >> 8) & 3, ks2 = e >> 10;
            int quarter = ks2 / 9, t = ks2 - quarter * 9;
            int cg = quarter * 32 + lq * 8 + j;
            wo_pk[e] = (oc < 27) ? f2bf(om_weight[(oc * 128 + cg) * 9 + t])
                                 : (short)0;
        }
    }
}

__global__ __launch_bounds__(256, 2) void fused_kernel(
    const unsigned short* __restrict__ catT, const short* __restrict__ wd_pk,
    const short* __restrict__ wo_pk, const float* __restrict__ om_bias,
    float* __restrict__ out)
{
    __shared__ float T[4 * 576];               // 9,216 B (per-wave 16x36)
    const int tid = threadIdx.x;
    const int lane = tid & 63, wv = tid >> 6;
    const int l16 = lane & 15, lq = lane >> 4;
    const int gw = blockIdx.x * 4 + wv;
    const int b = gw >> 8, tile = gw & 255;
    const int h = tile >> 2, w0 = (tile & 3) << 4;
    const int pxx = w0 + l16;
    const unsigned short* cb = catT + (size_t)b * 4096 * 128;
    const short8 zf = {0, 0, 0, 0, 0, 0, 0, 0};

    // ---- phase 1: om conv, named-register double buffer ----
    auto loadB1 = [&](int s) -> short8 {       // by-value return: SROA-safe
        int quarter = s / 9, t = s - quarter * 9;
        int ky = t / 3, kx = t - ky * 3;
        int yy = h - 1 + ky, xx = pxx - 1 + kx;
        bool ok = (yy >= 0) & (yy <= 63) & (xx >= 0) & (xx <= 63);
        int yc = min(max(yy, 0), 63), xc = min(max(xx, 0), 63);
        short8 v = *(const short8*)(cb + (yc * 64 + xc) * 128
                                       + quarter * 32 + lq * 8);
        return ok ? v : zf;
    };
    auto loadA1 = [&](int s, int m) -> short8 {
        return *(const short8*)(wo_pk + (size_t)(s * 4 + lq) * 256
                                      + (m * 16 + l16) * 8);
    };
    float4v oacc0 = {0.f, 0.f, 0.f, 0.f};
    float4v oacc1 = {0.f, 0.f, 0.f, 0.f};
    short8 bC = loadB1(0), a0C = loadA1(0, 0), a1C = loadA1(0, 1);
#pragma unroll
    for (int s = 0; s < 36; s++) {
        short8 bN = zf, a0N = zf, a1N = zf;
        if (s + 1 < 36) {                      // static after unroll
            bN  = loadB1(s + 1);
            a0N = loadA1(s + 1, 0);
            a1N = loadA1(s + 1, 1);
        }
        oacc0 = __builtin_amdgcn_mfma_f32_16x16x32_bf16(a0C, bC, oacc0, 0, 0, 0);
        oacc1 = __builtin_amdgcn_mfma_f32_16x16x32_bf16(a1C, bC, oacc1, 0, 0, 0);
        bC = bN; a0C = a0N; a1C = a1N;
    }

    // ---- phase 2: wave-private transpose -> omv (constant-index only) ----
    float* Tw = T + wv * 576;
#pragma unroll
    for (int r = 0; r < 4; r++) {
        Tw[l16 * 36 + lq * 4 + r]      = oacc0[r];   // oc = lq*4+r
        Tw[l16 * 36 + 16 + lq * 4 + r] = oacc1[r];   // oc = 16+lq*4+r
    }
    __syncthreads();
    float omv[28];
#pragma unroll
    for (int jj = 0; jj < 7; jj++) {
        float4v tv = *(const float4v*)&Tw[l16 * 36 + jj * 4];
        omv[jj * 4 + 0] = tv[0]; omv[jj * 4 + 1] = tv[1];
        omv[jj * 4 + 2] = tv[2]; omv[jj * 4 + 3] = tv[3];
    }
#pragma unroll
    for (int j = 0; j < 27; j++) omv[j] += om_bias[j];

    // ---- phase 3: deform, per-tap 16-load batch in named regs ----
    float4v acc0 = {0.f, 0.f, 0.f, 0.f}, acc1 = {0.f, 0.f, 0.f, 0.f};
    float4v acc2 = {0.f, 0.f, 0.f, 0.f}, acc3 = {0.f, 0.f, 0.f, 0.f};
#pragma unroll
    for (int t = 0; t < 9; t++) {
        const int ky = t / 3, kx = t - ky * 3;
        float dy = omv[2 * t], dx = omv[2 * t + 1];
        float mm = 1.f / (1.f + __expf(-omv[18 + t]));   // sigmoid(mask)
        float yf = (float)(h - 1 + ky) + dy;
        float xf = (float)(pxx - 1 + kx) + dx;
        float fy = floorf(yf), fx = floorf(xf);
        int y0 = (int)fy, x0 = (int)fx;
        float wy = yf - fy, wx = xf - fx;
        bool vy0 = (y0 >= 0) & (y0 < 64);
        bool vy1 = (y0 >= -1) & (y0 < 63);
        bool vx0 = (x0 >= 0) & (x0 < 64);
        bool vx1 = (x0 >= -1) & (x0 < 63);
        float a0 = (1.f - wy) * mm, a1 = wy * mm;
        float W00 = a0 * (1.f - wx) * (float)(vy0 & vx0);
        float W01 = a0 * wx         * (float)(vy0 & vx1);
        float W10 = a1 * (1.f - wx) * (float)(vy1 & vx0);
        float W11 = a1 * wx         * (float)(vy1 & vx1);
        // taps clamped INDEPENDENTLY: clamp(y0+1), not clamp(y0)+1
        int iy0 = min(max(y0, 0), 63),     ix0 = min(max(x0, 0), 63);
        int iy1 = min(max(y0 + 1, 0), 63), ix1 = min(max(x0 + 1, 0), 63);
        const unsigned short* p00 = cb + (iy0 * 64 + ix0) * 128 + lq * 8;
        const unsigned short* p01 = cb + (iy0 * 64 + ix1) * 128 + lq * 8;
        const unsigned short* p10 = cb + (iy1 * 64 + ix0) * 128 + lq * 8;
        const unsigned short* p11 = cb + (iy1 * 64 + ix1) * 128 + lq * 8;
        // 8 corner loads (qh=0: c0..31 at +0; qh=1: c32..63 at +32)
        short8 c00a = *(const short8*)p00,        c01a = *(const short8*)p01;
        short8 c10a = *(const short8*)p10,        c11a = *(const short8*)p11;
        short8 c00b = *(const short8*)(p00 + 32), c01b = *(const short8*)(p01 + 32);
        short8 c10b = *(const short8*)(p10 + 32), c11b = *(const short8*)(p11 + 32);
        // 8 A-frag loads for steps 2t (qh=0) and 2t+1 (qh=1)
        const short* D0 = wd_pk + (size_t)((2 * t) * 4 + lq) * 512;
        const short* D1 = wd_pk + (size_t)((2 * t + 1) * 4 + lq) * 512;
        short8 d00 = *(const short8*)(D0 + l16 * 8);
        short8 d01 = *(const short8*)(D0 + (16 + l16) * 8);
        short8 d02 = *(const short8*)(D0 + (32 + l16) * 8);
        short8 d03 = *(const short8*)(D0 + (48 + l16) * 8);
        short8 d10 = *(const short8*)(D1 + l16 * 8);
        short8 d11 = *(const short8*)(D1 + (16 + l16) * 8);
        short8 d12 = *(const short8*)(D1 + (32 + l16) * 8);
        short8 d13 = *(const short8*)(D1 + (48 + l16) * 8);
        short8 bfr0, bfr1;
#pragma unroll
        for (int j = 0; j < 8; j++) {
            float v0 = W00 * bf2f((unsigned short)c00a[j])
                     + W01 * bf2f((unsigned short)c01a[j])
                     + W10 * bf2f((unsigned short)c10a[j])
                     + W11 * bf2f((unsigned short)c11a[j]);
            float v1 = W00 * bf2f((unsigned short)c00b[j])
                     + W01 * bf2f((unsigned short)c01b[j])
                     + W10 * bf2f((unsigned short)c10b[j])
                     + W11 * bf2f((unsigned short)c11b[j]);
            bfr0[j] = f2bf(v0);
            bfr1[j] = f2bf(v1);
        }
        acc0 = __builtin_amdgcn_mfma_f32_16x16x32_bf16(d00, bfr0, acc0, 0, 0, 0);
        acc1 = __builtin_amdgcn_mfma_f32_16x16x32_bf16(d01, bfr0, acc1, 0, 0, 0);
        acc2 = __builtin_amdgcn_mfma_f32_16x16x32_bf16(d02, bfr0, acc2, 0, 0, 0);
        acc3 = __builtin_amdgcn_mfma_f32_16x16x32_bf16(d03, bfr0, acc3, 0, 0, 0);
        acc0 = __builtin_amdgcn_mfma_f32_16x16x32_bf16(d10, bfr1, acc0, 0, 0, 0);
        acc1 = __builtin_amdgcn_mfma_f32_16x16x32_bf16(d11, bfr1, acc1, 0, 0, 0);
        acc2 = __builtin_amdgcn_mfma_f32_16x16x32_bf16(d12, bfr1, acc2, 0, 0, 0);
        acc3 = __builtin_amdgcn_mfma_f32_16x16x32_bf16(d13, bfr1, acc3, 0, 0, 0);
    }

    // store: o = mt*16 + lq*4 + r, px = w0 + l16
    float* ob = out + (size_t)(b * 64) * 4096 + h * 64 + w0 + l16;
#pragma unroll
    for (int r = 0; r < 4; r++) ob[(lq * 4 + r) * 4096]      = acc0[r];
#pragma unroll
    for (int r = 0; r < 4; r++) ob[(16 + lq * 4 + r) * 4096] = acc1[r];
#pragma unroll
    for (int r = 0; r < 4; r++) ob[(32 + lq * 4 + r) * 4096] = acc2[r];
#pragma unroll
    for (int r = 0; r < 4; r++) ob[(48 + lq * 4 + r) * 4096] = acc3[r];
}

extern "C" void kernel_launch(void* const* d_in, const int* in_sizes, int n_in,
                              void* d_out, int out_size, void* d_ws, size_t ws_size,
                              hipStream_t stream)
{
    const float* feat      = (const float*)d_in[0];
    const float* deg       = (const float*)d_in[1];
    const float* weight    = (const float*)d_in[2];
    const float* om_weight = (const float*)d_in[3];
    const float* om_bias   = (const float*)d_in[4];
    float* out = (float*)d_out;
    short* wss = (short*)d_ws;
    unsigned short* catT = (unsigned short*)(wss + CATT_OFF);

    hipLaunchKernelGGL(prep_transpose, dim3(800), dim3(256), 0, stream,
                       feat, deg, weight, om_weight, catT,
                       wss, wss + WO_PK_OFF);
    hipLaunchKernelGGL(fused_kernel,   dim3(512), dim3(256), 0, stream,
                       catT, wss, wss + WO_PK_OFF, om_bias, out);
}

// Round 10
// 115.649 us; speedup vs baseline: 2.2066x; 1.0319x over previous
//
#include <hip/hip_runtime.h>
#include <math.h>

// B=8, C=64, H=W=64, O=64, K=3, KK=9, HW=4096
// prep_transpose: NCHW fp32 -> catT[b][hw][128] bf16 + MFMA A-frag weight
//                 packing (identical math to rounds 6-9, verified).
// fused_kernel:   per-wave (16 px): om conv (K=1152) -> wave-private
//                 transpose -> deformable conv (K=576).
// Orientation (HW-validated rounds 4-9):
//   A = weights: lane(l16,lq) holds W[m=tile*16+l16][k=step*32+lq*8+j]
//   B = samples: lane(l16,lq) holds S[k=step*32+lq*8+j][n=px(l16)]
//   C/D: col(=px)=lane&15, row(=m)=(lane>>4)*4+reg
//
// ROUND-10 CHANGES (r9 plateau = weight re-stream through VMEM):
//   * A-frags staged block-wide into LDS (dbuf): wo_pk per-quarter (18KB),
//     wd_pk per-tap (8KB). 4-wave duplication + 2048x L2 re-read removed.
//   * all staging / prefetch in NAMED registers only (r8 scratch lesson).
//   * b = blockIdx&7: image-per-XCD affinity for catT L2 locality.
//
// ws layout (shorts):
//   [0,     36864)  wd_pk : idx=((s*4+lq)*64+o16)*8+j, s=t*2+qh (18 steps)
//   [36864, 73728)  wo_pk : idx=((s*4+lq)*32+o32)*8+j, s=quarter*9+t (36)
//   [73728, +4194304B) catT bf16[b][hw][128] (feat c0..63, deg c64..127)
#define WO_PK_OFF 36864
#define CATT_OFF  73728

typedef short  short8  __attribute__((ext_vector_type(8)));
typedef float  float4v __attribute__((ext_vector_type(4)));

static __device__ __forceinline__ short f2bf(float f) {
    unsigned int u = __builtin_bit_cast(unsigned int, f);
    u += 0x7FFFu + ((u >> 16) & 1u);   // round-to-nearest-even
    return (short)(u >> 16);
}
static __device__ __forceinline__ float bf2f(unsigned short u) {
    return __builtin_bit_cast(float, (unsigned int)u << 16);
}

// blocks [0,512): transpose; blocks [512,800): weight packing.
__global__ __launch_bounds__(256) void prep_transpose(
    const float* __restrict__ feat, const float* __restrict__ deg,
    const float* __restrict__ weight, const float* __restrict__ om_weight,
    unsigned short* __restrict__ catT,
    short* __restrict__ wd_pk, short* __restrict__ wo_pk)
{
    __shared__ unsigned short T[64 * 136];
    const int tid = threadIdx.x;
    if (blockIdx.x < 512) {
        const int b = blockIdx.x >> 6, h = blockIdx.x & 63;
        const int lane = tid & 63, wv = tid >> 6;
#pragma unroll
        for (int cc = 0; cc < 32; cc++) {
            int c = wv * 32 + cc;              // wave-uniform
            const float* src = (c < 64)
                ? (feat + (size_t)(b * 64 + c) * 4096)
                : (deg  + (size_t)(b * 64 + (c - 64)) * 4096);
            T[lane * 136 + c] = (unsigned short)f2bf(src[h * 64 + lane]);
        }
        __syncthreads();
        const int px = tid >> 2, seg = tid & 3;
        unsigned short* dst =
            catT + (size_t)(b * 4096 + h * 64 + px) * 128 + seg * 32;
#pragma unroll
        for (int j = 0; j < 4; j++)
            *(uint4*)(dst + j * 8) = *(const uint4*)&T[px * 136 + seg * 32 + j * 8];
    } else {
        int idx = (blockIdx.x - 512) * 256 + tid;   // covers exactly 73728
        if (idx < 36864) {
            int j = idx & 7, o = (idx >> 3) & 63;
            int lq = (idx >> 9) & 3, ks = idx >> 11;
            int t = ks >> 1, c = (ks & 1) * 32 + lq * 8 + j;
            wd_pk[idx] = f2bf(weight[(o * 64 + c) * 9 + t]);
        } else {
            int e = idx - 36864;
            int j = e & 7, oc = (e >> 3) & 31;
            int lq = (e >> 8) & 3, ks2 = e >> 10;
            int quarter = ks2 / 9, t = ks2 - quarter * 9;
            int cg = quarter * 32 + lq * 8 + j;
            wo_pk[e] = (oc < 27) ? f2bf(om_weight[(oc * 128 + cg) * 9 + t])
                                 : (short)0;
        }
    }
}

__global__ __launch_bounds__(256, 2) void fused_kernel(
    const unsigned short* __restrict__ catT, const short* __restrict__ wd_pk,
    const short* __restrict__ wo_pk, const float* __restrict__ om_bias,
    float* __restrict__ out)
{
    // 36,864 B LDS union:
    //   phase 1: A1[2][1152] short8 (full 36,864 B)
    //   phase 2/3: Tw float[2304] (9,216 B) | A3[2][512] short8 (16,384 B)
    __shared__ short8 Lraw[2304];
    short8* A1 = Lraw;
    float*  Tw = (float*)Lraw;
    short8* A3 = Lraw + 576;                    // byte offset 9,216

    const int tid = threadIdx.x;
    const int lane = tid & 63, wv = tid >> 6;
    const int l16 = lane & 15, lq = lane >> 4;
    const int b = blockIdx.x & 7;               // image -> XCD affinity
    const int h = blockIdx.x >> 3;              // 0..63
    const int w0 = wv << 4;                     // wave owns 16 px of the row
    const int pxx = w0 + l16;
    const unsigned short* cb = catT + (size_t)b * 4096 * 128;
    const short8 zf = {0, 0, 0, 0, 0, 0, 0, 0};

    // B-frag gather for om conv: tap t of quarter q at this lane's pixel.
    auto loadB1 = [&](int q, int t) -> short8 {
        int ky = t / 3, kx = t - ky * 3;
        int yy = h - 1 + ky, xx = pxx - 1 + kx;
        bool ok = (yy >= 0) & (yy <= 63) & (xx >= 0) & (xx <= 63);
        int yc = min(max(yy, 0), 63), xc = min(max(xx, 0), 63);
        short8 v = *(const short8*)(cb + (yc * 64 + xc) * 128
                                       + q * 32 + lq * 8);
        return ok ? v : zf;
    };

    // ---------------- phase 1: om conv, LDS-staged A (dbuf) ----------------
    {   // stage quarter 0 into buf 0
        const short8* src = (const short8*)wo_pk;
        short8 g0 = src[tid], g1 = src[tid + 256];
        short8 g2 = src[tid + 512], g3 = src[tid + 768];
        short8 g4 = zf; if (tid < 128) g4 = src[tid + 1024];
        A1[tid] = g0; A1[tid + 256] = g1; A1[tid + 512] = g2; A1[tid + 768] = g3;
        if (tid < 128) A1[tid + 1024] = g4;
    }
    __syncthreads();

    float4v oacc0 = {0.f, 0.f, 0.f, 0.f};
    float4v oacc1 = {0.f, 0.f, 0.f, 0.f};
#pragma unroll
    for (int q = 0; q < 4; q++) {
        const int bufo = (q & 1) * 1152;
        // issue staging loads for quarter q+1 (land during compute)
        short8 g0 = zf, g1 = zf, g2 = zf, g3 = zf, g4 = zf;
        if (q < 3) {
            const short8* src = (const short8*)(wo_pk + (q + 1) * 9216);
            g0 = src[tid]; g1 = src[tid + 256];
            g2 = src[tid + 512]; g3 = src[tid + 768];
            if (tid < 128) g4 = src[tid + 1024];
        }
        // all 9 B-frags of this quarter in flight (named regs)
        short8 b0 = loadB1(q, 0), b1 = loadB1(q, 1), b2 = loadB1(q, 2);
        short8 b3 = loadB1(q, 3), b4 = loadB1(q, 4), b5 = loadB1(q, 5);
        short8 b6 = loadB1(q, 6), b7 = loadB1(q, 7), b8 = loadB1(q, 8);
#define PH1_STEP(SL, BREG) { \
        short8 af0 = A1[bufo + (SL) * 128 + lq * 32 + l16]; \
        short8 af1 = A1[bufo + (SL) * 128 + lq * 32 + 16 + l16]; \
        oacc0 = __builtin_amdgcn_mfma_f32_16x16x32_bf16(af0, BREG, oacc0, 0, 0, 0); \
        oacc1 = __builtin_amdgcn_mfma_f32_16x16x32_bf16(af1, BREG, oacc1, 0, 0, 0); }
        PH1_STEP(0, b0) PH1_STEP(1, b1) PH1_STEP(2, b2)
        PH1_STEP(3, b3) PH1_STEP(4, b4) PH1_STEP(5, b5)
        PH1_STEP(6, b6) PH1_STEP(7, b7) PH1_STEP(8, b8)
#undef PH1_STEP
        if (q < 3) {
            const int bufn = ((q + 1) & 1) * 1152;
            A1[bufn + tid] = g0; A1[bufn + tid + 256] = g1;
            A1[bufn + tid + 512] = g2; A1[bufn + tid + 768] = g3;
            if (tid < 128) A1[bufn + tid + 1024] = g4;
        }
        __syncthreads();   // quarter boundary: staging visible, reads done
    }

    // ---- phase 2: wave-private transpose -> omv (constant indices) ----
    float* Twv = Tw + wv * 576;
#pragma unroll
    for (int r = 0; r < 4; r++) {
        Twv[l16 * 36 + lq * 4 + r]      = oacc0[r];   // oc = lq*4+r
        Twv[l16 * 36 + 16 + lq * 4 + r] = oacc1[r];   // oc = 16+lq*4+r
    }
    // issue tap-0 wd_pk staging loads now (land across the barrier)
    short8 s0 = ((const short8*)wd_pk)[tid];
    short8 s1 = ((const short8*)wd_pk)[tid + 256];
    __syncthreads();
    float omv[28];
#pragma unroll
    for (int jj = 0; jj < 7; jj++) {
        float4v tv = *(const float4v*)&Twv[l16 * 36 + jj * 4];
        omv[jj * 4 + 0] = tv[0]; omv[jj * 4 + 1] = tv[1];
        omv[jj * 4 + 2] = tv[2]; omv[jj * 4 + 3] = tv[3];
    }
#pragma unroll
    for (int j = 0; j < 27; j++) omv[j] += om_bias[j];
    A3[tid] = s0; A3[tid + 256] = s1;          // tap 0 -> buf 0
    __syncthreads();

    // ---- phase 3: deform, LDS-staged A (dbuf per tap) ----
    float4v acc0 = {0.f, 0.f, 0.f, 0.f}, acc1 = {0.f, 0.f, 0.f, 0.f};
    float4v acc2 = {0.f, 0.f, 0.f, 0.f}, acc3 = {0.f, 0.f, 0.f, 0.f};
#pragma unroll
    for (int t = 0; t < 9; t++) {
        const int bo = (t & 1) * 512;
        // staging loads for tap t+1
        short8 g0 = zf, g1 = zf;
        if (t < 8) {
            const short8* src = (const short8*)wd_pk + (t + 1) * 512;
            g0 = src[tid]; g1 = src[tid + 256];
        }
        // bilinear coefficients for this tap (inline, no arrays)
        const int ky = t / 3, kx = t - ky * 3;
        float dy = omv[2 * t], dx = omv[2 * t + 1];
        float mm = 1.f / (1.f + __expf(-omv[18 + t]));   // sigmoid(mask)
        float yf = (float)(h - 1 + ky) + dy;
        float xf = (float)(pxx - 1 + kx) + dx;
        float fy = floorf(yf), fx = floorf(xf);
        int y0 = (int)fy, x0 = (int)fx;
        float wy = yf - fy, wx = xf - fx;
        bool vy0 = (y0 >= 0) & (y0 < 64);
        bool vy1 = (y0 >= -1) & (y0 < 63);
        bool vx0 = (x0 >= 0) & (x0 < 64);
        bool vx1 = (x0 >= -1) & (x0 < 63);
        float a0 = (1.f - wy) * mm, a1 = wy * mm;
        float W00 = a0 * (1.f - wx) * (float)(vy0 & vx0);
        float W01 = a0 * wx         * (float)(vy0 & vx1);
        float W10 = a1 * (1.f - wx) * (float)(vy1 & vx0);
        float W11 = a1 * wx         * (float)(vy1 & vx1);
        // taps clamped INDEPENDENTLY: clamp(y0+1), not clamp(y0)+1
        int iy0 = min(max(y0, 0), 63),     ix0 = min(max(x0, 0), 63);
        int iy1 = min(max(y0 + 1, 0), 63), ix1 = min(max(x0 + 1, 0), 63);
        const unsigned short* p00 = cb + (iy0 * 64 + ix0) * 128 + lq * 8;
        const unsigned short* p01 = cb + (iy0 * 64 + ix1) * 128 + lq * 8;
        const unsigned short* p10 = cb + (iy1 * 64 + ix0) * 128 + lq * 8;
        const unsigned short* p11 = cb + (iy1 * 64 + ix1) * 128 + lq * 8;
        // 8 corner loads (qh=0 at +0, qh=1 at +32 shorts), all in flight
        short8 c00a = *(const short8*)p00,        c01a = *(const short8*)p01;
        short8 c10a = *(const short8*)p10,        c11a = *(const short8*)p11;
        short8 c00b = *(const short8*)(p00 + 32), c01b = *(const short8*)(p01 + 32);
        short8 c10b = *(const short8*)(p10 + 32), c11b = *(const short8*)(p11 + 32);
        // 8 A-frags from LDS: slot = (qh*4+lq)*64 + m*16 + l16
        short8 d00 = A3[bo + lq * 64 + l16];
        short8 d01 = A3[bo + lq * 64 + 16 + l16];
        short8 d02 = A3[bo + lq * 64 + 32 + l16];
        short8 d03 = A3[bo + lq * 64 + 48 + l16];
        short8 d10 = A3[bo + 256 + lq * 64 + l16];
        short8 d11 = A3[bo + 256 + lq * 64 + 16 + l16];
        short8 d12 = A3[bo + 256 + lq * 64 + 32 + l16];
        short8 d13 = A3[bo + 256 + lq * 64 + 48 + l16];
        short8 bfr0, bfr1;
#pragma unroll
        for (int j = 0; j < 8; j++) {
            float v0 = W00 * bf2f((unsigned short)c00a[j])
                     + W01 * bf2f((unsigned short)c01a[j])
                     + W10 * bf2f((unsigned short)c10a[j])
                     + W11 * bf2f((unsigned short)c11a[j]);
            float v1 = W00 * bf2f((unsigned short)c00b[j])
                     + W01 * bf2f((unsigned short)c01b[j])
                     + W10 * bf2f((unsigned short)c10b[j])
                     + W11 * bf2f((unsigned short)c11b[j]);
            bfr0[j] = f2bf(v0);
            bfr1[j] = f2bf(v1);
        }
        acc0 = __builtin_amdgcn_mfma_f32_16x16x32_bf16(d00, bfr0, acc0, 0, 0, 0);
        acc1 = __builtin_amdgcn_mfma_f32_16x16x32_bf16(d01, bfr0, acc1, 0, 0, 0);
        acc2 = __builtin_amdgcn_mfma_f32_16x16x32_bf16(d02, bfr0, acc2, 0, 0, 0);
        acc3 = __builtin_amdgcn_mfma_f32_16x16x32_bf16(d03, bfr0, acc3, 0, 0, 0);
        acc0 = __builtin_amdgcn_mfma_f32_16x16x32_bf16(d10, bfr1, acc0, 0, 0, 0);
        acc1 = __builtin_amdgcn_mfma_f32_16x16x32_bf16(d11, bfr1, acc1, 0, 0, 0);
        acc2 = __builtin_amdgcn_mfma_f32_16x16x32_bf16(d12, bfr1, acc2, 0, 0, 0);
        acc3 = __builtin_amdgcn_mfma_f32_16x16x32_bf16(d13, bfr1, acc3, 0, 0, 0);
        if (t < 8) {
            const int bn = ((t + 1) & 1) * 512;
            A3[bn + tid] = g0; A3[bn + tid + 256] = g1;
        }
        __syncthreads();   // tap boundary
    }

    // store: o = mt*16 + lq*4 + r, px = w0 + l16
    float* ob = out + (size_t)(b * 64) * 4096 + h * 64 + w0 + l16;
#pragma unroll
    for (int r = 0; r < 4; r++) ob[(lq * 4 + r) * 4096]      = acc0[r];
#pragma unroll
    for (int r = 0; r < 4; r++) ob[(16 + lq * 4 + r) * 4096] = acc1[r];
#pragma unroll
    for (int r = 0; r < 4; r++) ob[(32 + lq * 4 + r) * 4096] = acc2[r];
#pragma unroll
    for (int r = 0; r < 4; r++) ob[(48 + lq * 4 + r) * 4096] = acc3[r];
}

extern "C" void kernel_launch(void* const* d_in, const int* in_sizes, int n_in,
                              void* d_out, int out_size, void* d_ws, size_t ws_size,
                              hipStream_t stream)
{
    const float* feat      = (const float*)d_in[0];
    const float* deg       = (const float*)d_in[1];
    const float* weight    = (const float*)d_in[2];
    const float* om_weight = (const float*)d_in[3];
    const float* om_bias   = (const float*)d_in[4];
    float* out = (float*)d_out;
    short* wss = (short*)d_ws;
    unsigned short* catT = (unsigned short*)(wss + CATT_OFF);

    hipLaunchKernelGGL(prep_transpose, dim3(800), dim3(256), 0, stream,
                       feat, deg, weight, om_weight, catT,
                       wss, wss + WO_PK_OFF);
    hipLaunchKernelGGL(fused_kernel,   dim3(512), dim3(256), 0, stream,
                       catT, wss, wss + WO_PK_OFF, om_bias, out);
}